// Round 3
// baseline (338.933 us; speedup 1.0000x reference)
//
#include <hip/hip_runtime.h>

// LocallyConnectedLayer MI355X — R5: cache-line amortization (Tj=6).
//  - 150 blocks x 512 thr (8 waves, wave owns 16 b-rows), M=128 (no w re-read)
//  - j-tile 6: x lines/output /3, weight runs 216B contiguous per thread
//  - A in regs (8-tap windows, funnel-shift per jj), B dbuf LDS (2x79.9KB)
//  - one barrier/chunk, prefetch overlaps MFMA (R3/R4 proven structure)
// out[b,o,i,j] = bias[o,i,j] + sum_{c,kh,kw} x[b,c,i+kh,j+kw]*W[c,o,i,j,kh,kw]

typedef __bf16 bf16x8 __attribute__((ext_vector_type(8)));
typedef float f32x4 __attribute__((ext_vector_type(4)));
typedef unsigned long long u64;
typedef unsigned int u32t;
typedef unsigned short u16t;

struct __attribute__((packed, aligned(8))) uf4 { f32x4 v; };   // 8B-aligned 16B
struct __attribute__((packed, aligned(8))) uf2 { float2 v; };

__device__ __forceinline__ u16t f2bf(float f) {
  union { float f; u32t u; } v; v.f = f;
  u32t r = v.u + 0x7fffu + ((v.u >> 16) & 1u);  // RTNE
  return (u16t)(r >> 16);
}
__device__ __forceinline__ u32t pk2(float a, float b) {
  return (u32t)f2bf(a) | ((u32t)f2bf(b) << 16);
}
__device__ __forceinline__ u64 pk3(float a, float b, float c) {
  return (u64)f2bf(a) | ((u64)f2bf(b) << 16) | ((u64)f2bf(c) << 32);  // hi16=0 pad
}
__device__ __forceinline__ bf16x8 mk_af(u64 lo, u64 hi) {
  union { u64 q[2]; bf16x8 v; } u;
  u.q[0] = lo; u.q[1] = hi;
  return u.v;
}

// x:    [128,64,32,32]  strides(f32) b:65536 c:1024 h:32 w:1
// wgt:  [64(c),64(o),30,30,3,3]; (c,o) run of 54 floats at P*8100 + ij0*9
// bias: [64,30,30]; out: [128,64,30,30] strides b:57600 o:900 ij:1

__global__ __launch_bounds__(512, 2) void lcl_kernel(
    const float* __restrict__ x, const float* __restrict__ wgt,
    const float* __restrict__ bias, float* __restrict__ out) {
  // 150 blocks -> XCD-contiguous bijective swizzle (150 = 6*19 + 2*18)
  int bid = blockIdx.x;
  int xcd = bid & 7, sg = bid >> 3;
  int t = (xcd < 6 ? xcd * 19 : 114 + (xcd - 6) * 18) + sg;
  int i = t / 5;
  int j0 = (t % 5) * 6;        // 0,6,12,18,24
  int ij0 = i * 30 + j0;       // even

  // B LDS: [buf:2][dj:6][o:64][104 u16]; k' = (cc*3+kh)*4+kw, kw=3 pads = 0
  __shared__ __align__(16) u16t Bt[2 * 6 * 64 * 104];  // 159744 B

  const int tid  = threadIdx.x;
  const int wave = tid >> 6;   // 0..7: b-row group AND cc for weight loads
  const int lane = tid & 63;
  const int lrow = lane & 15;
  const int q    = lane >> 4;

  // ---- x: lane's own b row; 6 runs g = s*8 + q*2 + tt, 8 taps (32B) each
  const float* xb = x + (wave * 16 + lrow) * 65536 + i * 32 + j0;
  int xoff[3][2];
#pragma unroll
  for (int s = 0; s < 3; ++s)
#pragma unroll
    for (int tt = 0; tt < 2; ++tt) {
      int g = s * 8 + q * 2 + tt, cc = g / 3, kh = g - cc * 3;
      xoff[s][tt] = cc * 1024 + kh * 32;
    }

  // ---- weight: thread owns pair (cc=wave, o=lane): 216B contiguous run
  const float* wb = wgt + (size_t)wave * 518400 + lane * 8100 + ij0 * 9;

  f32x4 av[3][2][2];   // x prefetch: 6 runs x 32B
  f32x4 wv[13];        // weight prefetch: floats 0..51
  float2 wv2;          // floats 52,53

#define GF(K) ((K) < 52 ? wv[(K) >> 2][(K)&3] : ((K) == 52 ? wv2.x : wv2.y))

#define LOAD_CHUNK(C0)                                                      \
  {                                                                         \
    const float* xc = xb + (C0) * 1024;                                     \
    _Pragma("unroll") for (int s = 0; s < 3; ++s)                           \
    _Pragma("unroll") for (int tt = 0; tt < 2; ++tt) {                      \
      const float* xq = xc + xoff[s][tt];                                   \
      av[s][tt][0] = ((const uf4*)xq)->v;                                   \
      av[s][tt][1] = ((const uf4*)(xq + 4))->v;                             \
    }                                                                       \
    const float* wq = wb + (size_t)(C0) * 518400;                           \
    _Pragma("unroll") for (int e = 0; e < 13; ++e)                          \
      wv[e] = ((const uf4*)(wq + e * 4))->v;                                \
    wv2 = ((const uf2*)(wq + 52))->v;                                       \
  }

  f32x4 acc[6][4];
#pragma unroll
  for (int a = 0; a < 6; ++a)
#pragma unroll
    for (int n = 0; n < 4; ++n) acc[a][n] = f32x4{0.f, 0.f, 0.f, 0.f};

  LOAD_CHUNK(0)

  for (int chunk = 0; chunk < 8; ++chunk) {
    u16t* B = Bt + (chunk & 1) * 39936;

    // ---- B slab write from prefetched regs (18 x 8B stores; pk3 zero-pads)
    //      All 96 read-slots rewritten every chunk -> no LDS zero-init needed.
#pragma unroll
    for (int dj = 0; dj < 6; ++dj) {
      u16t* Bp = B + dj * 6656 + lane * 104 + wave * 12;
#pragma unroll
      for (int kh = 0; kh < 3; ++kh) {
        const int k0 = dj * 9 + kh * 3;
        float f0 = GF(k0), f1 = GF(k0 + 1), f2v = GF(k0 + 2);
        *(u64*)&Bp[kh * 4] = pk3(f0, f1, f2v);
      }
    }

    // ---- pack own x runs: 8 taps -> 2 u64 of bf16
    u64 rb[3][2][2];
#pragma unroll
    for (int s = 0; s < 3; ++s)
#pragma unroll
      for (int tt = 0; tt < 2; ++tt) {
        f32x4 a0 = av[s][tt][0], a1 = av[s][tt][1];
        rb[s][tt][0] = (u64)pk2(a0[0], a0[1]) | ((u64)pk2(a0[2], a0[3]) << 32);
        rb[s][tt][1] = (u64)pk2(a1[0], a1[1]) | ((u64)pk2(a1[2], a1[3]) << 32);
      }

    __syncthreads();

    // ---- issue next chunk's globals; latency hides under MFMA phase
    if (chunk < 7) LOAD_CHUNK((chunk + 1) * 8)

    // ---- MFMA phase: A windows from regs, B from LDS
#pragma unroll
    for (int s = 0; s < 3; ++s) {
#pragma unroll
      for (int jj = 0; jj < 6; ++jj) {
        bf16x8 bfr[4];
#pragma unroll
        for (int nt = 0; nt < 4; ++nt)
          bfr[nt] = *reinterpret_cast<const bf16x8*>(
              &B[jj * 6656 + (nt * 16 + lrow) * 104 + s * 32 + q * 8]);
        // af slot kw = x tap (jj+kw); kw=3 slot multiplies B pad = 0
        u64 lo, hi;
        if (jj == 0) {
          lo = rb[s][0][0];
          hi = rb[s][1][0];
        } else if (jj < 4) {
          lo = (rb[s][0][0] >> (16 * jj)) | (rb[s][0][1] << (16 * (4 - jj)));
          hi = (rb[s][1][0] >> (16 * jj)) | (rb[s][1][1] << (16 * (4 - jj)));
        } else if (jj == 4) {
          lo = rb[s][0][1];
          hi = rb[s][1][1];
        } else {
          lo = rb[s][0][1] >> 16;
          hi = rb[s][1][1] >> 16;
        }
        bf16x8 af = mk_af(lo, hi);
#pragma unroll
        for (int nt = 0; nt < 4; ++nt)
          acc[jj][nt] = __builtin_amdgcn_mfma_f32_16x16x32_bf16(
              af, bfr[nt], acc[jj][nt], 0, 0, 0);
      }
    }
  }

  // ---- epilogue: D[row=q*4+r][col=lrow]; row->b (wave*16+), col->o
  const int b_out = wave * 16 + q * 4;
#pragma unroll
  for (int nt = 0; nt < 4; ++nt) {
    int o = nt * 16 + lrow;
    const float* bp = bias + o * 900 + ij0;
    f32x4 b03 = ((const uf4*)bp)->v;
    float2 b45 = ((const uf2*)(bp + 4))->v;
#pragma unroll
    for (int r = 0; r < 4; ++r) {
      int b = b_out + r;
      float* op = out + b * 57600 + o * 900 + ij0;
      f32x4 r03;
      r03[0] = acc[0][nt][r] + b03[0];
      r03[1] = acc[1][nt][r] + b03[1];
      r03[2] = acc[2][nt][r] + b03[2];
      r03[3] = acc[3][nt][r] + b03[3];
      float2 r45;
      r45.x = acc[4][nt][r] + b45.x;
      r45.y = acc[5][nt][r] + b45.y;
      ((uf4*)op)->v = r03;
      ((uf2*)(op + 4))->v = r45;
    }
  }
}

extern "C" void kernel_launch(void* const* d_in, const int* in_sizes, int n_in,
                              void* d_out, int out_size, void* d_ws,
                              size_t ws_size, hipStream_t stream) {
  const float* x    = (const float*)d_in[0];
  const float* wgt  = (const float*)d_in[1];
  const float* bias = (const float*)d_in[2];
  float* out        = (float*)d_out;
  lcl_kernel<<<dim3(150), dim3(512), 0, stream>>>(x, wgt, bias, out);
}

// Round 6
// 322.006 us; speedup vs baseline: 1.0526x; 1.0526x over previous
//
#include <hip/hip_runtime.h>

// LocallyConnectedLayer MI355X — R8: R7 with prep-kernel store-stride fix.
//  - prep kernel: x f32 -> bf16 rows Xb[c][h][b][32] (row = one 64B line;
//    lane-groups of 16 consecutive b read 16 consecutive lines = 1KB bursts)
//    FIX vs R6/R7: store stride s*8 u16 (16B), was s*16 u16 (32B) -> half of
//    every row stale + cross-row clobber = the identical absmax-175 failures.
//  - main: 600 blocks = 30 i x 5 jg(Tj=6) x 2 og x 2 bg; 256 thr; M=64 N=32
//  - A: ONE align(4) 16B load per run at byte offset j0*2 (taps j0..j0+7),
//    compile-time funnel shifts only (R4-proven pattern)
//  - B: thread-owned 216B contiguous f32 weight runs (R5-verified path)
//  - B dbuf LDS (2x39.9KB), 1 barrier/chunk, prefetch overlaps MFMA
//  - fallback to proven R4 kernel if ws too small
// out[b,o,i,j] = bias[o,i,j] + sum_{c,kh,kw} x[b,c,i+kh,j+kw]*W[c,o,i,j,kh,kw]

typedef __bf16 bf16x8 __attribute__((ext_vector_type(8)));
typedef float f32x4 __attribute__((ext_vector_type(4)));
typedef unsigned long long u64;
typedef unsigned int u32t;
typedef unsigned short u16t;

struct __attribute__((packed, aligned(8))) uf4 { f32x4 v; };
struct __attribute__((packed, aligned(8))) uf2 { float2 v; };
struct __attribute__((packed, aligned(4))) uq2 { u64 x, y; };  // 16B, 4-aligned
struct __attribute__((aligned(16))) ull2 { u64 x, y; };

__device__ __forceinline__ u16t f2bf(float f) {
  union { float f; u32t u; } v; v.f = f;
  u32t r = v.u + 0x7fffu + ((v.u >> 16) & 1u);  // RTNE
  return (u16t)(r >> 16);
}
__device__ __forceinline__ u32t pk2(float a, float b) {
  return (u32t)f2bf(a) | ((u32t)f2bf(b) << 16);
}
__device__ __forceinline__ u64 pk3(float a, float b, float c) {
  return (u64)f2bf(a) | ((u64)f2bf(b) << 16) | ((u64)f2bf(c) << 32);  // hi16=0
}
__device__ __forceinline__ bf16x8 mk_af(u64 lo, u64 hi) {
  union { u64 q[2]; bf16x8 v; } u;
  u.q[0] = lo; u.q[1] = hi;
  return u.v;
}

// x:    [128,64,32,32]  strides(f32) b:65536 c:1024 h:32 w:1
// Xb:   [c 64][h 32][b 128][w 32] bf16  (row = 64B = one line)
// wgt:  [64(c),64(o),30,30,3,3]; (c,o) run of 54 floats at P*8100 + ij0*9
// bias: [64,30,30]; out: [128,64,30,30] strides b:57600 o:900 ij:1

__global__ __launch_bounds__(256) void lcl_prep_x(const float* __restrict__ x,
                                                  u16t* __restrict__ Xb) {
  int gid = blockIdx.x * 256 + threadIdx.x;  // [0, 262144) = (c*32+h)*128 + b
  int b  = gid & 127;
  int ch = gid >> 7;                         // c*32 + h
  const float* src = x + (size_t)b * 65536 + ch * 32;  // 16B-aligned
  u16t* dst = Xb + (size_t)gid * 32;
  u64 qv[8];
#pragma unroll
  for (int s = 0; s < 8; ++s) {
    f32x4 a = ((const uf4*)(src + s * 4))->v;
    qv[s] = (u64)pk2(a[0], a[1]) | ((u64)pk2(a[2], a[3]) << 32);
  }
#pragma unroll
  for (int s = 0; s < 4; ++s) {
    ull2 w; w.x = qv[2 * s]; w.y = qv[2 * s + 1];
    *(ull2*)(dst + s * 8) = w;   // FIX: 8 u16 = 16B per ull2 (was s*16)
  }
}

__global__ __launch_bounds__(256, 2) void lcl_main(
    const u16t* __restrict__ Xb, const float* __restrict__ wgt,
    const float* __restrict__ bias, float* __restrict__ out) {
  // 600 blocks -> XCD-contiguous swizzle (600 = 8*75 exact); jg fastest so
  // j-siblings, og-twins, bg-twins are adjacent on the same XCD (L2 share)
  int bid = blockIdx.x;
  int xcd = bid & 7, sg = bid >> 3;
  int t = xcd * 75 + sg;            // [0,600)
  int jg = t % 5;
  int r  = t / 5;                   // i*4 + og*2 + bg
  int bg = r & 1, og = (r >> 1) & 1, i = r >> 2;
  int j0 = jg * 6;
  int ij0 = i * 30 + j0;            // even

  // B LDS: [buf 2][dj 6][o 32][104 u16]; k' = (cc*3+kh)*4+kw, kw=3 pads = 0
  __shared__ __align__(16) u16t Bt[2 * 6 * 32 * 104];  // 79872 B

  const int tid  = threadIdx.x;
  const int wave = tid >> 6;
  const int lane = tid & 63;
  const int lrow = lane & 15;
  const int q    = lane >> 4;

  // ---- A: per-lane bf16 taps j0..j0+7 = one 16B load at byte j0*2 (4-aligned)
  const int b_x = bg * 64 + wave * 16 + lrow;
  const char* xbase = (const char*)Xb;
  u32t xoff[3][2];                  // byte offsets (chunk 0), incl. j0*2
#pragma unroll
  for (int s = 0; s < 3; ++s)
#pragma unroll
    for (int tt = 0; tt < 2; ++tt) {
      int g = s * 8 + q * 2 + tt, cc = g / 3, kh = g - cc * 3;
      xoff[s][tt] = (u32t)(((cc * 32 + (i + kh)) * 128 + b_x) * 64 + j0 * 2);
    }

  // ---- B: thread owns run (cc = tid>>5, o = og*32 + (tid&31)): 216B contiguous
  const int ccw = tid >> 5, ow = tid & 31;
  const float* wb = wgt + ((size_t)ccw * 64 + og * 32 + ow) * 8100 + ij0 * 9;

  uq2   rq[3][2];      // raw A taps j0..j0+7 per run (already bf16)
  f32x4 wv[13];        // w prefetch floats 0..51
  float2 wv2;          // floats 52,53

#define GF(K) ((K) < 52 ? wv[(K) >> 2][(K)&3] : ((K) == 52 ? wv2.x : wv2.y))

#define LOAD_CHUNK(C0)                                                      \
  {                                                                         \
    const size_t xadv = (size_t)(C0) * 262144;                              \
    _Pragma("unroll") for (int s = 0; s < 3; ++s)                           \
    _Pragma("unroll") for (int tt = 0; tt < 2; ++tt)                        \
      rq[s][tt] = *(const uq2*)(xbase + xadv + xoff[s][tt]);                \
    const float* wq = wb + (size_t)(C0) * 518400;                           \
    _Pragma("unroll") for (int e = 0; e < 13; ++e)                          \
      wv[e] = ((const uf4*)(wq + e * 4))->v;                                \
    wv2 = ((const uf2*)(wq + 52))->v;                                       \
  }

  f32x4 acc[6][2];
#pragma unroll
  for (int a = 0; a < 6; ++a)
#pragma unroll
    for (int n = 0; n < 2; ++n) acc[a][n] = f32x4{0.f, 0.f, 0.f, 0.f};

  LOAD_CHUNK(0)

  for (int chunk = 0; chunk < 8; ++chunk) {
    u16t* B = Bt + (chunk & 1) * 19968;

    // ---- B slab write from prefetched regs (18 x 8B, pk3 zero-pads kw=3;
    //      all 96 read-slots x 32 rows rewritten every chunk)
#pragma unroll
    for (int dj = 0; dj < 6; ++dj) {
      u16t* Bp = B + dj * 3328 + ow * 104 + ccw * 12;
#pragma unroll
      for (int kh = 0; kh < 3; ++kh) {
        const int k0 = dj * 9 + kh * 3;
        *(u64*)&Bp[kh * 4] = pk3(GF(k0), GF(k0 + 1), GF(k0 + 2));
      }
    }

    // ---- snapshot A taps (rq is overwritten by the next-chunk prefetch)
    u64 rb[3][2][2];
#pragma unroll
    for (int s = 0; s < 3; ++s)
#pragma unroll
      for (int tt = 0; tt < 2; ++tt) {
        rb[s][tt][0] = rq[s][tt].x;   // taps j0..j0+3
        rb[s][tt][1] = rq[s][tt].y;   // taps j0+4..j0+7
      }

    __syncthreads();

    // ---- issue next chunk's globals; latency hides under MFMA phase
    if (chunk < 7) LOAD_CHUNK((chunk + 1) * 8)

    // ---- MFMA phase: A from regs (compile-time funnel per jj), B from LDS
#pragma unroll
    for (int s = 0; s < 3; ++s) {
#pragma unroll
      for (int jj = 0; jj < 6; ++jj) {
        bf16x8 bfr0 = *(const bf16x8*)&B[jj * 3328 + lrow * 104 + s * 32 + q * 8];
        bf16x8 bfr1 = *(const bf16x8*)&B[jj * 3328 + (16 + lrow) * 104 + s * 32 + q * 8];
        // af slot kw = tap (j0+jj+kw); slot 3 garbage multiplies B pad = 0
        u64 lo, hi;
        if (jj == 0) {
          lo = rb[s][0][0];
          hi = rb[s][1][0];
        } else if (jj < 4) {
          lo = (rb[s][0][0] >> (16 * jj)) | (rb[s][0][1] << (64 - 16 * jj));
          hi = (rb[s][1][0] >> (16 * jj)) | (rb[s][1][1] << (64 - 16 * jj));
        } else if (jj == 4) {
          lo = rb[s][0][1];
          hi = rb[s][1][1];
        } else {
          lo = rb[s][0][1] >> 16;
          hi = rb[s][1][1] >> 16;
        }
        bf16x8 af = mk_af(lo, hi);
        acc[jj][0] = __builtin_amdgcn_mfma_f32_16x16x32_bf16(af, bfr0, acc[jj][0], 0, 0, 0);
        acc[jj][1] = __builtin_amdgcn_mfma_f32_16x16x32_bf16(af, bfr1, acc[jj][1], 0, 0, 0);
      }
    }
  }

  // ---- epilogue: D[row=q*4+rr][col=lrow]; 3 float2 per (b,o) over j0..j0+5
  const int b0 = bg * 64 + wave * 16 + q * 4;
#pragma unroll
  for (int nt = 0; nt < 2; ++nt) {
    int o = og * 32 + nt * 16 + lrow;
    const float* bp = bias + o * 900 + ij0;
    float2 bv0 = ((const uf2*)bp)->v;
    float2 bv1 = ((const uf2*)(bp + 2))->v;
    float2 bv2 = ((const uf2*)(bp + 4))->v;
#pragma unroll
    for (int rr = 0; rr < 4; ++rr) {
      float* op = out + (size_t)(b0 + rr) * 57600 + o * 900 + ij0;
      float2 r0{acc[0][nt][rr] + bv0.x, acc[1][nt][rr] + bv0.y};
      float2 r1{acc[2][nt][rr] + bv1.x, acc[3][nt][rr] + bv1.y};
      float2 r2{acc[4][nt][rr] + bv2.x, acc[5][nt][rr] + bv2.y};
      ((uf2*)op)->v = r0;
      ((uf2*)(op + 2))->v = r1;
      ((uf2*)(op + 4))->v = r2;
    }
  }
}

// ================= fallback: proven R4 kernel (ws too small) =================
__global__ __launch_bounds__(256, 2) void lcl_r4(
    const float* __restrict__ x, const float* __restrict__ wgt,
    const float* __restrict__ bias, float* __restrict__ out) {
  int blk = blockIdx.x;
  int xcd = blk & 7, sg = blk >> 3;
  int t = xcd * 56 + (xcd < 2 ? xcd : 2) + sg;
  int i = t / 15;
  int j0 = (t % 15) * 2;
  int ij0 = i * 30 + j0;

  __shared__ __align__(16) u16t Bt[2 * 2 * 64 * 104];

  const int tid  = threadIdx.x;
  const int wave = tid >> 6;
  const int lane = tid & 63;
  const int lrow = lane & 15;
  const int q    = lane >> 4;

  {
    u64* zp = (u64*)Bt;
#pragma unroll
    for (int k = 0; k < 26; ++k) zp[tid + k * 256] = 0ull;
  }

  int xoffF[3][2];
#pragma unroll
  for (int s = 0; s < 3; ++s)
#pragma unroll
    for (int tt = 0; tt < 2; ++tt) {
      int g = s * 8 + q * 2 + tt, cc = g / 3, kh = g - cc * 3;
      xoffF[s][tt] = cc * 1024 + kh * 32;
    }
  const float* xb0 = x + (wave * 32 + lrow) * 65536 + i * 32 + j0;
  const float* xb1 = xb0 + 16 * 65536;

  const int o_w = tid & 63;
  const float* wb0 = wgt + (size_t)wave * 518400 + o_w * 8100 + ij0 * 9;
  const float* wb1 = wb0 + (size_t)4 * 518400;

  f32x4 av[2][3][2];
  f32x4 wv[2][5];

#define LOAD_CHUNK4(C0)                                                       \
  {                                                                           \
    const float* xc0 = xb0 + (C0) * 1024;                                     \
    const float* xc1 = xb1 + (C0) * 1024;                                     \
    _Pragma("unroll") for (int s = 0; s < 3; ++s)                             \
    _Pragma("unroll") for (int tt = 0; tt < 2; ++tt) {                        \
      av[0][s][tt] = ((const uf4*)(xc0 + xoffF[s][tt]))->v;                   \
      av[1][s][tt] = ((const uf4*)(xc1 + xoffF[s][tt]))->v;                   \
    }                                                                         \
    const float* w0 = wb0 + (size_t)(C0) * 518400;                            \
    const float* w1 = wb1 + (size_t)(C0) * 518400;                            \
    _Pragma("unroll") for (int e = 0; e < 4; ++e) {                           \
      wv[0][e] = ((const uf4*)(w0 + e * 4))->v;                               \
      wv[1][e] = ((const uf4*)(w1 + e * 4))->v;                               \
    }                                                                         \
    wv[0][4] = ((const uf4*)(w0 + 14))->v;                                    \
    wv[1][4] = ((const uf4*)(w1 + 14))->v;                                    \
  }

  f32x4 acc[2][2][4];
#pragma unroll
  for (int a = 0; a < 2; ++a)
#pragma unroll
    for (int b = 0; b < 2; ++b)
#pragma unroll
      for (int c = 0; c < 4; ++c) acc[a][b][c] = f32x4{0.f, 0.f, 0.f, 0.f};

  LOAD_CHUNK4(0)

  for (int chunk = 0; chunk < 8; ++chunk) {
    u16t* B = Bt + (chunk & 1) * 13312;
#pragma unroll
    for (int p = 0; p < 2; ++p) {
      int ccl = wave + 4 * p;
      u16t* Bp = B + o_w * 104 + ccl * 12;
      *(u32t*)&Bp[0] = pk2(wv[p][0][0], wv[p][0][1]);
      Bp[2]  = f2bf(wv[p][0][2]);
      Bp[4]  = f2bf(wv[p][0][3]);
      Bp[5]  = f2bf(wv[p][1][0]);
      Bp[6]  = f2bf(wv[p][1][1]);
      *(u32t*)&Bp[8] = pk2(wv[p][1][2], wv[p][1][3]);
      Bp[10] = f2bf(wv[p][2][0]);
      u16t* Bq = Bp + 6656;
      *(u32t*)&Bq[0] = pk2(wv[p][2][1], wv[p][2][2]);
      Bq[2]  = f2bf(wv[p][2][3]);
      Bq[4]  = f2bf(wv[p][3][0]);
      Bq[5]  = f2bf(wv[p][3][1]);
      Bq[6]  = f2bf(wv[p][3][2]);
      *(u32t*)&Bq[8] = pk2(wv[p][3][3], wv[p][4][2]);
      Bq[10] = f2bf(wv[p][4][3]);
    }

    u64 rb[2][3][2];
#pragma unroll
    for (int mt = 0; mt < 2; ++mt)
#pragma unroll
      for (int s = 0; s < 3; ++s)
#pragma unroll
        for (int tt = 0; tt < 2; ++tt) {
          const f32x4 vv = av[mt][s][tt];
          rb[mt][s][tt] = (u64)pk2(vv[0], vv[1]) | ((u64)pk2(vv[2], vv[3]) << 32);
        }

    __syncthreads();

    if (chunk < 7) LOAD_CHUNK4((chunk + 1) * 8)

#pragma unroll
    for (int s = 0; s < 3; ++s) {
      bf16x8 bfr[2][4];
#pragma unroll
      for (int jj = 0; jj < 2; ++jj)
#pragma unroll
        for (int nt = 0; nt < 4; ++nt)
          bfr[jj][nt] = *reinterpret_cast<const bf16x8*>(
              &B[jj * 6656 + (nt * 16 + lrow) * 104 + s * 32 + q * 8]);
#pragma unroll
      for (int mt = 0; mt < 2; ++mt)
#pragma unroll
        for (int jj = 0; jj < 2; ++jj) {
          u64 lo = rb[mt][s][0] >> (jj * 16);
          u64 hi = rb[mt][s][1] >> (jj * 16);
          bf16x8 af = mk_af(lo, hi);
#pragma unroll
          for (int nt = 0; nt < 4; ++nt)
            acc[mt][jj][nt] = __builtin_amdgcn_mfma_f32_16x16x32_bf16(
                af, bfr[jj][nt], acc[mt][jj][nt], 0, 0, 0);
        }
    }
  }

#pragma unroll
  for (int nt = 0; nt < 4; ++nt) {
    int o = nt * 16 + lrow;
    float2 bv = *(const float2*)(bias + o * 900 + ij0);
#pragma unroll
    for (int mt = 0; mt < 2; ++mt) {
#pragma unroll
      for (int rr = 0; rr < 4; ++rr) {
        int b = wave * 32 + mt * 16 + q * 4 + rr;
        float2 res;
        res.x = acc[mt][0][nt][rr] + bv.x;
        res.y = acc[mt][1][nt][rr] + bv.y;
        *(float2*)(out + b * 57600 + o * 900 + ij0) = res;
      }
    }
  }
}

extern "C" void kernel_launch(void* const* d_in, const int* in_sizes, int n_in,
                              void* d_out, int out_size, void* d_ws,
                              size_t ws_size, hipStream_t stream) {
  const float* x    = (const float*)d_in[0];
  const float* wgt  = (const float*)d_in[1];
  const float* bias = (const float*)d_in[2];
  float* out        = (float*)d_out;
  if (ws_size >= (size_t)16777216 && d_ws != nullptr) {
    lcl_prep_x<<<dim3(1024), dim3(256), 0, stream>>>(x, (u16t*)d_ws);
    lcl_main<<<dim3(600), dim3(256), 0, stream>>>((const u16t*)d_ws, wgt, bias, out);
  } else {
    lcl_r4<<<dim3(450), dim3(256), 0, stream>>>(x, wgt, bias, out);
  }
}

// Round 7
// 284.350 us; speedup vs baseline: 1.1920x; 1.1324x over previous
//
#include <hip/hip_runtime.h>

// LocallyConnectedLayer MI355X — R9: coalesced weight gather.
//  - R8-proven skeleton (x-prep bf16 rows, Tj=6, 600 blocks, A-in-regs,
//    dbuf B-LDS, 1 barrier/chunk, funnel-shift MFMA) kept byte-identical.
//  - NEW w path: 8 consecutive lanes share one 216B run (load k=(p,h): lane
//    (g8,e8) reads 16B at run(p*32+g8) + (h?88B:0) + e8*16B) -> 128B bursts,
//    ~16 lines/instr instead of 64 scattered. h=1 starts at float 22 so all
//    floats valid (22..31 double-written, same value, benign).
//  - loaded slivers go straight to LDS k'-slots: 64 ds_write_b16/thread/chunk
//    via 8 precomputed slot offsets + compile-time p*12 immediates.
//  - pads (kw=3 slots) zeroed once at start (+barrier), never overwritten.
//  - epilogue: merged uf4+uf2 stores (24->16 instrs), uf4+uf2 bias loads.
// out[b,o,i,j] = bias[o,i,j] + sum_{c,kh,kw} x[b,c,i+kh,j+kw]*W[c,o,i,j,kh,kw]

typedef __bf16 bf16x8 __attribute__((ext_vector_type(8)));
typedef float f32x4 __attribute__((ext_vector_type(4)));
typedef unsigned long long u64;
typedef unsigned int u32t;
typedef unsigned short u16t;

struct __attribute__((packed, aligned(8))) uf4 { f32x4 v; };
struct __attribute__((packed, aligned(4))) uf4a { f32x4 v; };  // 4B-aligned 16B
struct __attribute__((packed, aligned(8))) uf2 { float2 v; };
struct __attribute__((packed, aligned(4))) uq2 { u64 x, y; };  // 16B, 4-aligned
struct __attribute__((aligned(16))) ull2 { u64 x, y; };

__device__ __forceinline__ u16t f2bf(float f) {
  union { float f; u32t u; } v; v.f = f;
  u32t r = v.u + 0x7fffu + ((v.u >> 16) & 1u);  // RTNE
  return (u16t)(r >> 16);
}
__device__ __forceinline__ u32t pk2(float a, float b) {
  return (u32t)f2bf(a) | ((u32t)f2bf(b) << 16);
}
__device__ __forceinline__ bf16x8 mk_af(u64 lo, u64 hi) {
  union { u64 q[2]; bf16x8 v; } u;
  u.q[0] = lo; u.q[1] = hi;
  return u.v;
}

// x:    [128,64,32,32]  strides(f32) b:65536 c:1024 h:32 w:1
// Xb:   [c 64][h 32][b 128][w 32] bf16  (row = 64B = one line)
// wgt:  [64(c),64(o),30,30,3,3]; (c,o) run of 54 floats at P*8100 + ij0*9
// bias: [64,30,30]; out: [128,64,30,30] strides b:57600 o:900 ij:1

__global__ __launch_bounds__(256) void lcl_prep_x(const float* __restrict__ x,
                                                  u16t* __restrict__ Xb) {
  int gid = blockIdx.x * 256 + threadIdx.x;  // [0, 262144) = (c*32+h)*128 + b
  int b  = gid & 127;
  int ch = gid >> 7;                         // c*32 + h
  const float* src = x + (size_t)b * 65536 + ch * 32;  // 16B-aligned
  u16t* dst = Xb + (size_t)gid * 32;
  u64 qv[8];
#pragma unroll
  for (int s = 0; s < 8; ++s) {
    f32x4 a = ((const uf4*)(src + s * 4))->v;
    qv[s] = (u64)pk2(a[0], a[1]) | ((u64)pk2(a[2], a[3]) << 32);
  }
#pragma unroll
  for (int s = 0; s < 4; ++s) {
    ull2 w; w.x = qv[2 * s]; w.y = qv[2 * s + 1];
    *(ull2*)(dst + s * 8) = w;
  }
}

__global__ __launch_bounds__(256, 2) void lcl_main(
    const u16t* __restrict__ Xb, const float* __restrict__ wgt,
    const float* __restrict__ bias, float* __restrict__ out) {
  // 600 blocks -> XCD-contiguous swizzle (600 = 8*75 exact); jg fastest
  int bid = blockIdx.x;
  int xcd = bid & 7, sg = bid >> 3;
  int t = xcd * 75 + sg;            // [0,600)
  int jg = t % 5;
  int r  = t / 5;                   // i*4 + og*2 + bg
  int bg = r & 1, og = (r >> 1) & 1, i = r >> 2;
  int j0 = jg * 6;
  int ij0 = i * 30 + j0;            // even

  // B LDS: [buf 2][dj 6][o 32][104 u16]; slot = dj*3328+o*104+p*12+kh*4+kw
  __shared__ __align__(16) u16t Bt[2 * 6 * 32 * 104];  // 79872 B

  const int tid  = threadIdx.x;
  const int wave = tid >> 6;
  const int lane = tid & 63;
  const int lrow = lane & 15;
  const int q    = lane >> 4;

  // ---- zero-init whole B (pad slots kw=3 must stay 0; data slots are
  //      rewritten every chunk). Barrier before first data write.
  {
    u64* zp = (u64*)Bt;   // 9984 u64 = 39*256
#pragma unroll
    for (int k = 0; k < 39; ++k) zp[tid + k * 256] = 0ull;
  }

  // ---- A: per-lane bf16 taps j0..j0+7 = one 16B load at byte j0*2
  const int b_x = bg * 64 + wave * 16 + lrow;
  const char* xbase = (const char*)Xb;
  u32t xoff[3][2];
#pragma unroll
  for (int s = 0; s < 3; ++s)
#pragma unroll
    for (int tt = 0; tt < 2; ++tt) {
      int g = s * 8 + q * 2 + tt, cc = g / 3, kh = g - cc * 3;
      xoff[s][tt] = (u32t)(((cc * 32 + (i + kh)) * 128 + b_x) * 64 + j0 * 2);
    }

  // ---- W: 8-lane cooperative runs. e8 = seg lane, g8 = run o-slot.
  const int e8 = tid & 7, g8 = tid >> 3;
  const int o_w = og * 32 + g8;
  const int FO0 = e8 * 4;        // h=0: floats e8*4 .. +3   (0..31)
  const int FO1 = 22 + e8 * 4;   // h=1: floats 22+e8*4 .. +3 (22..53)
  int Pofs[8];                   // LDS u16 offsets (dj*3328 + kh*4 + kw)
#pragma unroll
  for (int jm = 0; jm < 8; ++jm) {
    int F = ((jm & 4) ? FO1 : FO0) + (jm & 3);
    Pofs[jm] = (F / 9) * 3328 + ((F % 9) / 3) * 4 + (F % 3);
  }
  const float* wb = wgt + (size_t)o_w * 8100 + ij0 * 9;

  uq2   rq[3][2];     // raw A taps
  f32x4 wreg[16];     // w slivers: k=(p,h) -> 4 floats of run (p, g8)

#define LOAD_CHUNK(C0)                                                      \
  {                                                                         \
    const size_t xadv = (size_t)(C0) * 262144;                              \
    _Pragma("unroll") for (int s = 0; s < 3; ++s)                           \
    _Pragma("unroll") for (int tt = 0; tt < 2; ++tt)                        \
      rq[s][tt] = *(const uq2*)(xbase + xadv + xoff[s][tt]);                \
    _Pragma("unroll") for (int k = 0; k < 16; ++k) {                        \
      const int p_ = k >> 1;                                                \
      const float* wq = wb + (size_t)((C0) + p_) * 518400 +                 \
                        ((k & 1) ? FO1 : FO0);                              \
      wreg[k] = ((const uf4a*)wq)->v;                                       \
    }                                                                       \
  }

  f32x4 acc[6][2];
#pragma unroll
  for (int a = 0; a < 6; ++a)
#pragma unroll
    for (int n = 0; n < 2; ++n) acc[a][n] = f32x4{0.f, 0.f, 0.f, 0.f};

  LOAD_CHUNK(0)
  __syncthreads();   // zeros visible before any B data write

  for (int chunk = 0; chunk < 8; ++chunk) {
    // ---- scatter w slivers to B slab (64 ds_write_b16; p*12 folds to imm)
    u16t* Bb = Bt + (chunk & 1) * 19968 + g8 * 104;
#pragma unroll
    for (int k = 0; k < 16; ++k) {
      const int p_ = k >> 1, h_ = k & 1;
#pragma unroll
      for (int m = 0; m < 4; ++m)
        (Bb + Pofs[h_ * 4 + m])[p_ * 12] = f2bf(wreg[k][m]);
    }

    // ---- snapshot A taps (rq overwritten by next prefetch)
    u64 rb[3][2][2];
#pragma unroll
    for (int s = 0; s < 3; ++s)
#pragma unroll
      for (int tt = 0; tt < 2; ++tt) {
        rb[s][tt][0] = rq[s][tt].x;
        rb[s][tt][1] = rq[s][tt].y;
      }

    __syncthreads();

    // ---- issue next chunk's globals; latency hides under MFMA phase
    if (chunk < 7) LOAD_CHUNK((chunk + 1) * 8)

    // ---- MFMA phase (unchanged, R8-verified)
#pragma unroll
    for (int s = 0; s < 3; ++s) {
#pragma unroll
      for (int jj = 0; jj < 6; ++jj) {
        bf16x8 bfr0 = *(const bf16x8*)&Bt[(chunk & 1) * 19968 + jj * 3328 +
                                          lrow * 104 + s * 32 + q * 8];
        bf16x8 bfr1 = *(const bf16x8*)&Bt[(chunk & 1) * 19968 + jj * 3328 +
                                          (16 + lrow) * 104 + s * 32 + q * 8];
        u64 lo, hi;
        if (jj == 0) {
          lo = rb[s][0][0];
          hi = rb[s][1][0];
        } else if (jj < 4) {
          lo = (rb[s][0][0] >> (16 * jj)) | (rb[s][0][1] << (64 - 16 * jj));
          hi = (rb[s][1][0] >> (16 * jj)) | (rb[s][1][1] << (64 - 16 * jj));
        } else if (jj == 4) {
          lo = rb[s][0][1];
          hi = rb[s][1][1];
        } else {
          lo = rb[s][0][1] >> 16;
          hi = rb[s][1][1] >> 16;
        }
        bf16x8 af = mk_af(lo, hi);
        acc[jj][0] = __builtin_amdgcn_mfma_f32_16x16x32_bf16(af, bfr0, acc[jj][0], 0, 0, 0);
        acc[jj][1] = __builtin_amdgcn_mfma_f32_16x16x32_bf16(af, bfr1, acc[jj][1], 0, 0, 0);
      }
    }
  }

  // ---- epilogue: merged 16B+8B stores; D[row=q*4+rr][col=lrow]
  const int b0 = bg * 64 + wave * 16 + q * 4;
#pragma unroll
  for (int nt = 0; nt < 2; ++nt) {
    int o = og * 32 + nt * 16 + lrow;
    const float* bp = bias + o * 900 + ij0;
    f32x4 b03 = ((const uf4*)bp)->v;
    float2 b45 = ((const uf2*)(bp + 4))->v;
#pragma unroll
    for (int rr = 0; rr < 4; ++rr) {
      float* op = out + (size_t)(b0 + rr) * 57600 + o * 900 + ij0;
      f32x4 r03;
      r03[0] = acc[0][nt][rr] + b03[0];
      r03[1] = acc[1][nt][rr] + b03[1];
      r03[2] = acc[2][nt][rr] + b03[2];
      r03[3] = acc[3][nt][rr] + b03[3];
      float2 r45;
      r45.x = acc[4][nt][rr] + b45.x;
      r45.y = acc[5][nt][rr] + b45.y;
      ((uf4*)op)->v = r03;
      ((uf2*)(op + 4))->v = r45;
    }
  }
}

// ================= fallback: proven R4 kernel (ws too small) =================
__global__ __launch_bounds__(256, 2) void lcl_r4(
    const float* __restrict__ x, const float* __restrict__ wgt,
    const float* __restrict__ bias, float* __restrict__ out) {
  int blk = blockIdx.x;
  int xcd = blk & 7, sg = blk >> 3;
  int t = xcd * 56 + (xcd < 2 ? xcd : 2) + sg;
  int i = t / 15;
  int j0 = (t % 15) * 2;
  int ij0 = i * 30 + j0;

  __shared__ __align__(16) u16t Bt[2 * 2 * 64 * 104];

  const int tid  = threadIdx.x;
  const int wave = tid >> 6;
  const int lane = tid & 63;
  const int lrow = lane & 15;
  const int q    = lane >> 4;

  {
    u64* zp = (u64*)Bt;
#pragma unroll
    for (int k = 0; k < 26; ++k) zp[tid + k * 256] = 0ull;
  }

  int xoffF[3][2];
#pragma unroll
  for (int s = 0; s < 3; ++s)
#pragma unroll
    for (int tt = 0; tt < 2; ++tt) {
      int g = s * 8 + q * 2 + tt, cc = g / 3, kh = g - cc * 3;
      xoffF[s][tt] = cc * 1024 + kh * 32;
    }
  const float* xb0 = x + (wave * 32 + lrow) * 65536 + i * 32 + j0;
  const float* xb1 = xb0 + 16 * 65536;

  const int o_w = tid & 63;
  const float* wb0 = wgt + (size_t)wave * 518400 + o_w * 8100 + ij0 * 9;
  const float* wb1 = wb0 + (size_t)4 * 518400;

  f32x4 av[2][3][2];
  f32x4 wv[2][5];

#define LOAD_CHUNK4(C0)                                                       \
  {                                                                           \
    const float* xc0 = xb0 + (C0) * 1024;                                     \
    const float* xc1 = xb1 + (C0) * 1024;                                     \
    _Pragma("unroll") for (int s = 0; s < 3; ++s)                             \
    _Pragma("unroll") for (int tt = 0; tt < 2; ++tt) {                        \
      av[0][s][tt] = ((const uf4*)(xc0 + xoffF[s][tt]))->v;                   \
      av[1][s][tt] = ((const uf4*)(xc1 + xoffF[s][tt]))->v;                   \
    }                                                                         \
    const float* w0 = wb0 + (size_t)(C0) * 518400;                            \
    const float* w1 = wb1 + (size_t)(C0) * 518400;                            \
    _Pragma("unroll") for (int e = 0; e < 4; ++e) {                           \
      wv[0][e] = ((const uf4*)(w0 + e * 4))->v;                               \
      wv[1][e] = ((const uf4*)(w1 + e * 4))->v;                               \
    }                                                                         \
    wv[0][4] = ((const uf4*)(w0 + 14))->v;                                    \
    wv[1][4] = ((const uf4*)(w1 + 14))->v;                                    \
  }

  f32x4 acc[2][2][4];
#pragma unroll
  for (int a = 0; a < 2; ++a)
#pragma unroll
    for (int b = 0; b < 2; ++b)
#pragma unroll
      for (int c = 0; c < 4; ++c) acc[a][b][c] = f32x4{0.f, 0.f, 0.f, 0.f};

  LOAD_CHUNK4(0)

  for (int chunk = 0; chunk < 8; ++chunk) {
    u16t* B = Bt + (chunk & 1) * 13312;
#pragma unroll
    for (int p = 0; p < 2; ++p) {
      int ccl = wave + 4 * p;
      u16t* Bp = B + o_w * 104 + ccl * 12;
      *(u32t*)&Bp[0] = pk2(wv[p][0][0], wv[p][0][1]);
      Bp[2]  = f2bf(wv[p][0][2]);
      Bp[4]  = f2bf(wv[p][0][3]);
      Bp[5]  = f2bf(wv[p][1][0]);
      Bp[6]  = f2bf(wv[p][1][1]);
      *(u32t*)&Bp[8] = pk2(wv[p][1][2], wv[p][1][3]);
      Bp[10] = f2bf(wv[p][2][0]);
      u16t* Bq = Bp + 6656;
      *(u32t*)&Bq[0] = pk2(wv[p][2][1], wv[p][2][2]);
      Bq[2]  = f2bf(wv[p][2][3]);
      Bq[4]  = f2bf(wv[p][3][0]);
      Bq[5]  = f2bf(wv[p][3][1]);
      Bq[6]  = f2bf(wv[p][3][2]);
      *(u32t*)&Bq[8] = pk2(wv[p][3][3], wv[p][4][2]);
      Bq[10] = f2bf(wv[p][4][3]);
    }

    u64 rb[2][3][2];
#pragma unroll
    for (int mt = 0; mt < 2; ++mt)
#pragma unroll
      for (int s = 0; s < 3; ++s)
#pragma unroll
        for (int tt = 0; tt < 2; ++tt) {
          const f32x4 vv = av[mt][s][tt];
          rb[mt][s][tt] = (u64)pk2(vv[0], vv[1]) | ((u64)pk2(vv[2], vv[3]) << 32);
        }

    __syncthreads();

    if (chunk < 7) LOAD_CHUNK4((chunk + 1) * 8)

#pragma unroll
    for (int s = 0; s < 3; ++s) {
      bf16x8 bfr[2][4];
#pragma unroll
      for (int jj = 0; jj < 2; ++jj)
#pragma unroll
        for (int nt = 0; nt < 4; ++nt)
          bfr[jj][nt] = *reinterpret_cast<const bf16x8*>(
              &B[jj * 6656 + (nt * 16 + lrow) * 104 + s * 32 + q * 8]);
#pragma unroll
      for (int mt = 0; mt < 2; ++mt)
#pragma unroll
        for (int jj = 0; jj < 2; ++jj) {
          u64 lo = rb[mt][s][0] >> (jj * 16);
          u64 hi = rb[mt][s][1] >> (jj * 16);
          bf16x8 af = mk_af(lo, hi);
#pragma unroll
          for (int nt = 0; nt < 4; ++nt)
            acc[mt][jj][nt] = __builtin_amdgcn_mfma_f32_16x16x32_bf16(
                af, bfr[jj][nt], acc[mt][jj][nt], 0, 0, 0);
        }
    }
  }

#pragma unroll
  for (int nt = 0; nt < 4; ++nt) {
    int o = nt * 16 + lrow;
    float2 bv = *(const float2*)(bias + o * 900 + ij0);
#pragma unroll
    for (int mt = 0; mt < 2; ++mt) {
#pragma unroll
      for (int rr = 0; rr < 4; ++rr) {
        int b = wave * 32 + mt * 16 + q * 4 + rr;
        float2 res;
        res.x = acc[mt][0][nt][rr] + bv.x;
        res.y = acc[mt][1][nt][rr] + bv.y;
        *(float2*)(out + b * 57600 + o * 900 + ij0) = res;
      }
    }
  }
}

extern "C" void kernel_launch(void* const* d_in, const int* in_sizes, int n_in,
                              void* d_out, int out_size, void* d_ws,
                              size_t ws_size, hipStream_t stream) {
  const float* x    = (const float*)d_in[0];
  const float* wgt  = (const float*)d_in[1];
  const float* bias = (const float*)d_in[2];
  float* out        = (float*)d_out;
  if (ws_size >= (size_t)16777216 && d_ws != nullptr) {
    lcl_prep_x<<<dim3(1024), dim3(256), 0, stream>>>(x, (u16t*)d_ws);
    lcl_main<<<dim3(600), dim3(256), 0, stream>>>((const u16t*)d_ws, wgt, bias, out);
  } else {
    lcl_r4<<<dim3(450), dim3(256), 0, stream>>>(x, wgt, bias, out);
  }
}

// Round 8
// 276.632 us; speedup vs baseline: 1.2252x; 1.0279x over previous
//
#include <hip/hip_runtime.h>

// LocallyConnectedLayer MI355X — R10: window-major x prep + LDS conflict fix.
//  - prep: x f32 -> Xb3[c][h][jg 5][b 128][8taps bf16] (16B per (row,window);
//    consecutive-b lanes read consecutive 16B -> 16 lines/instr, was 64)
//  - main: R9-proven skeleton; dj-plane stride 3328->3344 u16 (8-way LDS
//    write conflicts -> 2-way); w path / funnel MFMA / epilogue unchanged
//  - tiers: ws>=21MB new path; >=16.8MB exact R9; else R4
// out[b,o,i,j] = bias[o,i,j] + sum_{c,kh,kw} x[b,c,i+kh,j+kw]*W[c,o,i,j,kh,kw]

typedef __bf16 bf16x8 __attribute__((ext_vector_type(8)));
typedef float f32x4 __attribute__((ext_vector_type(4)));
typedef unsigned long long u64;
typedef unsigned int u32t;
typedef unsigned short u16t;

struct __attribute__((packed, aligned(8))) uf4 { f32x4 v; };
struct __attribute__((packed, aligned(4))) uf4a { f32x4 v; };  // 4B-aligned 16B
struct __attribute__((packed, aligned(8))) uf2 { float2 v; };
struct __attribute__((packed, aligned(4))) uq2 { u64 x, y; };  // 16B, 4-aligned
struct __attribute__((aligned(16))) ull2 { u64 x, y; };

__device__ __forceinline__ u16t f2bf(float f) {
  union { float f; u32t u; } v; v.f = f;
  u32t r = v.u + 0x7fffu + ((v.u >> 16) & 1u);  // RTNE
  return (u16t)(r >> 16);
}
__device__ __forceinline__ u32t pk2(float a, float b) {
  return (u32t)f2bf(a) | ((u32t)f2bf(b) << 16);
}
__device__ __forceinline__ bf16x8 mk_af(u64 lo, u64 hi) {
  union { u64 q[2]; bf16x8 v; } u;
  u.q[0] = lo; u.q[1] = hi;
  return u.v;
}

// x:    [128,64,32,32]  strides(f32) b:65536 c:1024 h:32 w:1
// Xb3:  [c 64][h 32][jg 5][b 128] x 16B (taps 6jg..6jg+7, bf16)
// Xb:   [c 64][h 32][b 128][w 32] bf16 (R9 tier)
// wgt:  [64(c),64(o),30,30,3,3]; (c,o) run of 54 floats at P*8100 + ij0*9
// bias: [64,30,30]; out: [128,64,30,30] strides b:57600 o:900 ij:1

// ============ prep (R10): window-major ============
__global__ __launch_bounds__(256) void lcl_prep_x3(const float* __restrict__ x,
                                                   u16t* __restrict__ Xb) {
  int gid = blockIdx.x * 256 + threadIdx.x;  // (c*32+h)*128 + b
  int b  = gid & 127;
  int ch = gid >> 7;
  const float* src = x + (size_t)b * 65536 + ch * 32;  // 16B-aligned
  u64 qv[8];  // qv[s] = taps 4s..4s+3 packed bf16
#pragma unroll
  for (int s = 0; s < 8; ++s) {
    f32x4 a = ((const uf4*)(src + s * 4))->v;
    qv[s] = (u64)pk2(a[0], a[1]) | ((u64)pk2(a[2], a[3]) << 32);
  }
  u16t* dst = Xb + ((size_t)ch * 5 * 128 + b) * 8;  // +jg*1024 u16 per window
  ull2 w;
  w.x = qv[0];                          w.y = qv[1];                          *(ull2*)(dst)        = w;  // jg0: 0-7
  w.x = (qv[1] >> 32) | (qv[2] << 32);  w.y = (qv[2] >> 32) | (qv[3] << 32);  *(ull2*)(dst + 1024) = w;  // jg1: 6-13
  w.x = qv[3];                          w.y = qv[4];                          *(ull2*)(dst + 2048) = w;  // jg2: 12-19
  w.x = (qv[4] >> 32) | (qv[5] << 32);  w.y = (qv[5] >> 32) | (qv[6] << 32);  *(ull2*)(dst + 3072) = w;  // jg3: 18-25
  w.x = qv[6];                          w.y = qv[7];                          *(ull2*)(dst + 4096) = w;  // jg4: 24-31
}

// ============ main (R10) ============
__global__ __launch_bounds__(256, 2) void lcl_main10(
    const u16t* __restrict__ Xb, const float* __restrict__ wgt,
    const float* __restrict__ bias, float* __restrict__ out) {
  int bid = blockIdx.x;
  int xcd = bid & 7, sg = bid >> 3;
  int t = xcd * 75 + sg;            // 600 = 8*75 exact
  int jg = t % 5;
  int r  = t / 5;
  int bg = r & 1, og = (r >> 1) & 1, i = r >> 2;
  int j0 = jg * 6;
  int ij0 = i * 30 + j0;

  // B LDS: [buf 2][dj 6 stride 3344][o 32][104]; slot = p*12+kh*4+kw
  __shared__ __align__(16) u16t Bt[2 * 20480];  // 81920 B (= 2 blocks/CU max)

  const int tid  = threadIdx.x;
  const int wave = tid >> 6;
  const int lane = tid & 63;
  const int lrow = lane & 15;
  const int q    = lane >> 4;

  {  // zero-init (pads + gaps stay 0); 10240 u64 = 40*256
    u64* zp = (u64*)Bt;
#pragma unroll
    for (int k = 0; k < 40; ++k) zp[tid + k * 256] = 0ull;
  }

  // ---- A: window-major; lane reads 16B at consecutive-b addresses
  const int b_x = bg * 64 + wave * 16 + lrow;
  const char* xbase = (const char*)Xb;
  u32t xoff[3][2];
#pragma unroll
  for (int s = 0; s < 3; ++s)
#pragma unroll
    for (int tt = 0; tt < 2; ++tt) {
      int g = s * 8 + q * 2 + tt, cc = g / 3, kh = g - cc * 3;
      xoff[s][tt] = (u32t)((((cc * 32 + (i + kh)) * 5 + jg) * 128 + b_x) * 16);
    }

  // ---- W: 8-lane cooperative runs (R9-proven)
  const int e8 = tid & 7, g8 = tid >> 3;
  const int o_w = og * 32 + g8;
  const int FO0 = e8 * 4;        // h=0: floats 0..31
  const int FO1 = 22 + e8 * 4;   // h=1: floats 22..53
  int Pofs[8];                   // dj*3344 + kh*4 + kw
#pragma unroll
  for (int jm = 0; jm < 8; ++jm) {
    int F = ((jm & 4) ? FO1 : FO0) + (jm & 3);
    Pofs[jm] = (F / 9) * 3344 + ((F % 9) / 3) * 4 + (F % 3);
  }
  const float* wb = wgt + (size_t)o_w * 8100 + ij0 * 9;

  ull2  rq[3][2];     // A taps j0..j0+7 (aligned 16B)
  f32x4 wreg[16];

#define LOAD_CHUNK10(C0)                                                    \
  {                                                                         \
    const size_t xadv = (size_t)(C0) * 327680;                              \
    _Pragma("unroll") for (int s = 0; s < 3; ++s)                           \
    _Pragma("unroll") for (int tt = 0; tt < 2; ++tt)                        \
      rq[s][tt] = *(const ull2*)(xbase + xadv + xoff[s][tt]);               \
    _Pragma("unroll") for (int k = 0; k < 16; ++k) {                        \
      const int p_ = k >> 1;                                                \
      const float* wq = wb + (size_t)((C0) + p_) * 518400 +                 \
                        ((k & 1) ? FO1 : FO0);                              \
      wreg[k] = ((const uf4a*)wq)->v;                                       \
    }                                                                       \
  }

  f32x4 acc[6][2];
#pragma unroll
  for (int a = 0; a < 6; ++a)
#pragma unroll
    for (int n = 0; n < 2; ++n) acc[a][n] = f32x4{0.f, 0.f, 0.f, 0.f};

  LOAD_CHUNK10(0)
  __syncthreads();   // zeros visible before first B data write

  for (int chunk = 0; chunk < 8; ++chunk) {
    // ---- scatter w slivers (64 ds_write_b16; dj-stride 3344 kills 8-way)
    u16t* Bb = Bt + (chunk & 1) * 20480 + g8 * 104;
#pragma unroll
    for (int k = 0; k < 16; ++k) {
      const int p_ = k >> 1, h_ = k & 1;
#pragma unroll
      for (int m = 0; m < 4; ++m)
        (Bb + Pofs[h_ * 4 + m])[p_ * 12] = f2bf(wreg[k][m]);
    }

    // ---- snapshot A taps
    u64 rb[3][2][2];
#pragma unroll
    for (int s = 0; s < 3; ++s)
#pragma unroll
      for (int tt = 0; tt < 2; ++tt) {
        rb[s][tt][0] = rq[s][tt].x;
        rb[s][tt][1] = rq[s][tt].y;
      }

    __syncthreads();

    if (chunk < 7) LOAD_CHUNK10((chunk + 1) * 8)

    // ---- MFMA phase (R8/R9-verified; stride 3344)
#pragma unroll
    for (int s = 0; s < 3; ++s) {
#pragma unroll
      for (int jj = 0; jj < 6; ++jj) {
        bf16x8 bfr0 = *(const bf16x8*)&Bt[(chunk & 1) * 20480 + jj * 3344 +
                                          lrow * 104 + s * 32 + q * 8];
        bf16x8 bfr1 = *(const bf16x8*)&Bt[(chunk & 1) * 20480 + jj * 3344 +
                                          (16 + lrow) * 104 + s * 32 + q * 8];
        u64 lo, hi;
        if (jj == 0) {
          lo = rb[s][0][0];
          hi = rb[s][1][0];
        } else if (jj < 4) {
          lo = (rb[s][0][0] >> (16 * jj)) | (rb[s][0][1] << (64 - 16 * jj));
          hi = (rb[s][1][0] >> (16 * jj)) | (rb[s][1][1] << (64 - 16 * jj));
        } else if (jj == 4) {
          lo = rb[s][0][1];
          hi = rb[s][1][1];
        } else {
          lo = rb[s][0][1] >> 16;
          hi = rb[s][1][1] >> 16;
        }
        bf16x8 af = mk_af(lo, hi);
        acc[jj][0] = __builtin_amdgcn_mfma_f32_16x16x32_bf16(af, bfr0, acc[jj][0], 0, 0, 0);
        acc[jj][1] = __builtin_amdgcn_mfma_f32_16x16x32_bf16(af, bfr1, acc[jj][1], 0, 0, 0);
      }
    }
  }

  // ---- epilogue (R9-proven)
  const int b0 = bg * 64 + wave * 16 + q * 4;
#pragma unroll
  for (int nt = 0; nt < 2; ++nt) {
    int o = og * 32 + nt * 16 + lrow;
    const float* bp = bias + o * 900 + ij0;
    f32x4 b03 = ((const uf4*)bp)->v;
    float2 b45 = ((const uf2*)(bp + 4))->v;
#pragma unroll
    for (int rr = 0; rr < 4; ++rr) {
      float* op = out + (size_t)(b0 + rr) * 57600 + o * 900 + ij0;
      f32x4 r03;
      r03[0] = acc[0][nt][rr] + b03[0];
      r03[1] = acc[1][nt][rr] + b03[1];
      r03[2] = acc[2][nt][rr] + b03[2];
      r03[3] = acc[3][nt][rr] + b03[3];
      float2 r45;
      r45.x = acc[4][nt][rr] + b45.x;
      r45.y = acc[5][nt][rr] + b45.y;
      ((uf4*)op)->v = r03;
      ((uf2*)(op + 4))->v = r45;
    }
  }
}

// ============ prep (R9 tier, proven) ============
__global__ __launch_bounds__(256) void lcl_prep_x(const float* __restrict__ x,
                                                  u16t* __restrict__ Xb) {
  int gid = blockIdx.x * 256 + threadIdx.x;
  int b  = gid & 127;
  int ch = gid >> 7;
  const float* src = x + (size_t)b * 65536 + ch * 32;
  u16t* dst = Xb + (size_t)gid * 32;
  u64 qv[8];
#pragma unroll
  for (int s = 0; s < 8; ++s) {
    f32x4 a = ((const uf4*)(src + s * 4))->v;
    qv[s] = (u64)pk2(a[0], a[1]) | ((u64)pk2(a[2], a[3]) << 32);
  }
#pragma unroll
  for (int s = 0; s < 4; ++s) {
    ull2 w; w.x = qv[2 * s]; w.y = qv[2 * s + 1];
    *(ull2*)(dst + s * 8) = w;
  }
}

// ============ main (R9 tier, proven) ============
__global__ __launch_bounds__(256, 2) void lcl_main9(
    const u16t* __restrict__ Xb, const float* __restrict__ wgt,
    const float* __restrict__ bias, float* __restrict__ out) {
  int bid = blockIdx.x;
  int xcd = bid & 7, sg = bid >> 3;
  int t = xcd * 75 + sg;
  int jg = t % 5;
  int r  = t / 5;
  int bg = r & 1, og = (r >> 1) & 1, i = r >> 2;
  int j0 = jg * 6;
  int ij0 = i * 30 + j0;

  __shared__ __align__(16) u16t Bt[2 * 6 * 32 * 104];

  const int tid  = threadIdx.x;
  const int wave = tid >> 6;
  const int lane = tid & 63;
  const int lrow = lane & 15;
  const int q    = lane >> 4;

  {
    u64* zp = (u64*)Bt;
#pragma unroll
    for (int k = 0; k < 39; ++k) zp[tid + k * 256] = 0ull;
  }

  const int b_x = bg * 64 + wave * 16 + lrow;
  const char* xbase = (const char*)Xb;
  u32t xoff[3][2];
#pragma unroll
  for (int s = 0; s < 3; ++s)
#pragma unroll
    for (int tt = 0; tt < 2; ++tt) {
      int g = s * 8 + q * 2 + tt, cc = g / 3, kh = g - cc * 3;
      xoff[s][tt] = (u32t)(((cc * 32 + (i + kh)) * 128 + b_x) * 64 + j0 * 2);
    }

  const int e8 = tid & 7, g8 = tid >> 3;
  const int o_w = og * 32 + g8;
  const int FO0 = e8 * 4;
  const int FO1 = 22 + e8 * 4;
  int Pofs[8];
#pragma unroll
  for (int jm = 0; jm < 8; ++jm) {
    int F = ((jm & 4) ? FO1 : FO0) + (jm & 3);
    Pofs[jm] = (F / 9) * 3328 + ((F % 9) / 3) * 4 + (F % 3);
  }
  const float* wb = wgt + (size_t)o_w * 8100 + ij0 * 9;

  uq2   rq[3][2];
  f32x4 wreg[16];

#define LOAD_CHUNK9(C0)                                                     \
  {                                                                         \
    const size_t xadv = (size_t)(C0) * 262144;                              \
    _Pragma("unroll") for (int s = 0; s < 3; ++s)                           \
    _Pragma("unroll") for (int tt = 0; tt < 2; ++tt)                        \
      rq[s][tt] = *(const uq2*)(xbase + xadv + xoff[s][tt]);                \
    _Pragma("unroll") for (int k = 0; k < 16; ++k) {                        \
      const int p_ = k >> 1;                                                \
      const float* wq = wb + (size_t)((C0) + p_) * 518400 +                 \
                        ((k & 1) ? FO1 : FO0);                              \
      wreg[k] = ((const uf4a*)wq)->v;                                       \
    }                                                                       \
  }

  f32x4 acc[6][2];
#pragma unroll
  for (int a = 0; a < 6; ++a)
#pragma unroll
    for (int n = 0; n < 2; ++n) acc[a][n] = f32x4{0.f, 0.f, 0.f, 0.f};

  LOAD_CHUNK9(0)
  __syncthreads();

  for (int chunk = 0; chunk < 8; ++chunk) {
    u16t* Bb = Bt + (chunk & 1) * 19968 + g8 * 104;
#pragma unroll
    for (int k = 0; k < 16; ++k) {
      const int p_ = k >> 1, h_ = k & 1;
#pragma unroll
      for (int m = 0; m < 4; ++m)
        (Bb + Pofs[h_ * 4 + m])[p_ * 12] = f2bf(wreg[k][m]);
    }

    u64 rb[3][2][2];
#pragma unroll
    for (int s = 0; s < 3; ++s)
#pragma unroll
      for (int tt = 0; tt < 2; ++tt) {
        rb[s][tt][0] = rq[s][tt].x;
        rb[s][tt][1] = rq[s][tt].y;
      }

    __syncthreads();

    if (chunk < 7) LOAD_CHUNK9((chunk + 1) * 8)

#pragma unroll
    for (int s = 0; s < 3; ++s) {
#pragma unroll
      for (int jj = 0; jj < 6; ++jj) {
        bf16x8 bfr0 = *(const bf16x8*)&Bt[(chunk & 1) * 19968 + jj * 3328 +
                                          lrow * 104 + s * 32 + q * 8];
        bf16x8 bfr1 = *(const bf16x8*)&Bt[(chunk & 1) * 19968 + jj * 3328 +
                                          (16 + lrow) * 104 + s * 32 + q * 8];
        u64 lo, hi;
        if (jj == 0) {
          lo = rb[s][0][0];
          hi = rb[s][1][0];
        } else if (jj < 4) {
          lo = (rb[s][0][0] >> (16 * jj)) | (rb[s][0][1] << (64 - 16 * jj));
          hi = (rb[s][1][0] >> (16 * jj)) | (rb[s][1][1] << (64 - 16 * jj));
        } else if (jj == 4) {
          lo = rb[s][0][1];
          hi = rb[s][1][1];
        } else {
          lo = rb[s][0][1] >> 16;
          hi = rb[s][1][1] >> 16;
        }
        bf16x8 af = mk_af(lo, hi);
        acc[jj][0] = __builtin_amdgcn_mfma_f32_16x16x32_bf16(af, bfr0, acc[jj][0], 0, 0, 0);
        acc[jj][1] = __builtin_amdgcn_mfma_f32_16x16x32_bf16(af, bfr1, acc[jj][1], 0, 0, 0);
      }
    }
  }

  const int b0 = bg * 64 + wave * 16 + q * 4;
#pragma unroll
  for (int nt = 0; nt < 2; ++nt) {
    int o = og * 32 + nt * 16 + lrow;
    const float* bp = bias + o * 900 + ij0;
    f32x4 b03 = ((const uf4*)bp)->v;
    float2 b45 = ((const uf2*)(bp + 4))->v;
#pragma unroll
    for (int rr = 0; rr < 4; ++rr) {
      float* op = out + (size_t)(b0 + rr) * 57600 + o * 900 + ij0;
      f32x4 r03;
      r03[0] = acc[0][nt][rr] + b03[0];
      r03[1] = acc[1][nt][rr] + b03[1];
      r03[2] = acc[2][nt][rr] + b03[2];
      r03[3] = acc[3][nt][rr] + b03[3];
      float2 r45;
      r45.x = acc[4][nt][rr] + b45.x;
      r45.y = acc[5][nt][rr] + b45.y;
      ((uf4*)op)->v = r03;
      ((uf2*)(op + 4))->v = r45;
    }
  }
}

// ============ fallback: proven R4 kernel ============
__global__ __launch_bounds__(256, 2) void lcl_r4(
    const float* __restrict__ x, const float* __restrict__ wgt,
    const float* __restrict__ bias, float* __restrict__ out) {
  int blk = blockIdx.x;
  int xcd = blk & 7, sg = blk >> 3;
  int t = xcd * 56 + (xcd < 2 ? xcd : 2) + sg;
  int i = t / 15;
  int j0 = (t % 15) * 2;
  int ij0 = i * 30 + j0;

  __shared__ __align__(16) u16t Bt[2 * 2 * 64 * 104];

  const int tid  = threadIdx.x;
  const int wave = tid >> 6;
  const int lane = tid & 63;
  const int lrow = lane & 15;
  const int q    = lane >> 4;

  {
    u64* zp = (u64*)Bt;
#pragma unroll
    for (int k = 0; k < 26; ++k) zp[tid + k * 256] = 0ull;
  }

  int xoffF[3][2];
#pragma unroll
  for (int s = 0; s < 3; ++s)
#pragma unroll
    for (int tt = 0; tt < 2; ++tt) {
      int g = s * 8 + q * 2 + tt, cc = g / 3, kh = g - cc * 3;
      xoffF[s][tt] = cc * 1024 + kh * 32;
    }
  const float* xb0 = x + (wave * 32 + lrow) * 65536 + i * 32 + j0;
  const float* xb1 = xb0 + 16 * 65536;

  const int o_w = tid & 63;
  const float* wb0 = wgt + (size_t)wave * 518400 + o_w * 8100 + ij0 * 9;
  const float* wb1 = wb0 + (size_t)4 * 518400;

  f32x4 av[2][3][2];
  f32x4 wv[2][5];

#define LOAD_CHUNK4(C0)                                                       \
  {                                                                           \
    const float* xc0 = xb0 + (C0) * 1024;                                     \
    const float* xc1 = xb1 + (C0) * 1024;                                     \
    _Pragma("unroll") for (int s = 0; s < 3; ++s)                             \
    _Pragma("unroll") for (int tt = 0; tt < 2; ++tt) {                        \
      av[0][s][tt] = ((const uf4*)(xc0 + xoffF[s][tt]))->v;                   \
      av[1][s][tt] = ((const uf4*)(xc1 + xoffF[s][tt]))->v;                   \
    }                                                                         \
    const float* w0 = wb0 + (size_t)(C0) * 518400;                            \
    const float* w1 = wb1 + (size_t)(C0) * 518400;                            \
    _Pragma("unroll") for (int e = 0; e < 4; ++e) {                           \
      wv[0][e] = ((const uf4*)(w0 + e * 4))->v;                               \
      wv[1][e] = ((const uf4*)(w1 + e * 4))->v;                               \
    }                                                                         \
    wv[0][4] = ((const uf4*)(w0 + 14))->v;                                    \
    wv[1][4] = ((const uf4*)(w1 + 14))->v;                                    \
  }

  f32x4 acc[2][2][4];
#pragma unroll
  for (int a = 0; a < 2; ++a)
#pragma unroll
    for (int b = 0; b < 2; ++b)
#pragma unroll
      for (int c = 0; c < 4; ++c) acc[a][b][c] = f32x4{0.f, 0.f, 0.f, 0.f};

  LOAD_CHUNK4(0)

  for (int chunk = 0; chunk < 8; ++chunk) {
    u16t* B = Bt + (chunk & 1) * 13312;
#pragma unroll
    for (int p = 0; p < 2; ++p) {
      int ccl = wave + 4 * p;
      u16t* Bp = B + o_w * 104 + ccl * 12;
      *(u32t*)&Bp[0] = pk2(wv[p][0][0], wv[p][0][1]);
      Bp[2]  = f2bf(wv[p][0][2]);
      Bp[4]  = f2bf(wv[p][0][3]);
      Bp[5]  = f2bf(wv[p][1][0]);
      Bp[6]  = f2bf(wv[p][1][1]);
      *(u32t*)&Bp[8] = pk2(wv[p][1][2], wv[p][1][3]);
      Bp[10] = f2bf(wv[p][2][0]);
      u16t* Bq = Bp + 6656;
      *(u32t*)&Bq[0] = pk2(wv[p][2][1], wv[p][2][2]);
      Bq[2]  = f2bf(wv[p][2][3]);
      Bq[4]  = f2bf(wv[p][3][0]);
      Bq[5]  = f2bf(wv[p][3][1]);
      Bq[6]  = f2bf(wv[p][3][2]);
      *(u32t*)&Bq[8] = pk2(wv[p][3][3], wv[p][4][2]);
      Bq[10] = f2bf(wv[p][4][3]);
    }

    u64 rb[2][3][2];
#pragma unroll
    for (int mt = 0; mt < 2; ++mt)
#pragma unroll
      for (int s = 0; s < 3; ++s)
#pragma unroll
        for (int tt = 0; tt < 2; ++tt) {
          const f32x4 vv = av[mt][s][tt];
          rb[mt][s][tt] = (u64)pk2(vv[0], vv[1]) | ((u64)pk2(vv[2], vv[3]) << 32);
        }

    __syncthreads();

    if (chunk < 7) LOAD_CHUNK4((chunk + 1) * 8)

#pragma unroll
    for (int s = 0; s < 3; ++s) {
      bf16x8 bfr[2][4];
#pragma unroll
      for (int jj = 0; jj < 2; ++jj)
#pragma unroll
        for (int nt = 0; nt < 4; ++nt)
          bfr[jj][nt] = *reinterpret_cast<const bf16x8*>(
              &B[jj * 6656 + (nt * 16 + lrow) * 104 + s * 32 + q * 8]);
#pragma unroll
      for (int mt = 0; mt < 2; ++mt)
#pragma unroll
        for (int jj = 0; jj < 2; ++jj) {
          u64 lo = rb[mt][s][0] >> (jj * 16);
          u64 hi = rb[mt][s][1] >> (jj * 16);
          bf16x8 af = mk_af(lo, hi);
#pragma unroll
          for (int nt = 0; nt < 4; ++nt)
            acc[mt][jj][nt] = __builtin_amdgcn_mfma_f32_16x16x32_bf16(
                af, bfr[jj][nt], acc[mt][jj][nt], 0, 0, 0);
        }
    }
  }

#pragma unroll
  for (int nt = 0; nt < 4; ++nt) {
    int o = nt * 16 + lrow;
    float2 bv = *(const float2*)(bias + o * 900 + ij0);
#pragma unroll
    for (int mt = 0; mt < 2; ++mt) {
#pragma unroll
      for (int rr = 0; rr < 4; ++rr) {
        int b = wave * 32 + mt * 16 + q * 4 + rr;
        float2 res;
        res.x = acc[mt][0][nt][rr] + bv.x;
        res.y = acc[mt][1][nt][rr] + bv.y;
        *(float2*)(out + b * 57600 + o * 900 + ij0) = res;
      }
    }
  }
}

extern "C" void kernel_launch(void* const* d_in, const int* in_sizes, int n_in,
                              void* d_out, int out_size, void* d_ws,
                              size_t ws_size, hipStream_t stream) {
  const float* x    = (const float*)d_in[0];
  const float* wgt  = (const float*)d_in[1];
  const float* bias = (const float*)d_in[2];
  float* out        = (float*)d_out;
  if (ws_size >= (size_t)20971520 && d_ws != nullptr) {
    lcl_prep_x3<<<dim3(1024), dim3(256), 0, stream>>>(x, (u16t*)d_ws);
    lcl_main10<<<dim3(600), dim3(256), 0, stream>>>((const u16t*)d_ws, wgt, bias, out);
  } else if (ws_size >= (size_t)16777216 && d_ws != nullptr) {
    lcl_prep_x<<<dim3(1024), dim3(256), 0, stream>>>(x, (u16t*)d_ws);
    lcl_main9<<<dim3(600), dim3(256), 0, stream>>>((const u16t*)d_ws, wgt, bias, out);
  } else {
    lcl_r4<<<dim3(450), dim3(256), 0, stream>>>(x, wgt, bias, out);
  }
}